// Round 4
// baseline (705.037 us; speedup 1.0000x reference)
//
#include <hip/hip_runtime.h>

// out = X[8192x4096] @ W^T, W[4096x4096] = scatter_add(values at (row,col)), row_ids sorted.
// R7: (a) GEMM switched 16x16x32 -> 32x32x16 MFMA (2382-2495 vs 2075 TF ceiling,
//     half the MFMA issue count; same LDS traffic/phase structure/vmcnt schedule).
//     Buffers reordered [A0|A1|B0|B1] so buf1 ds_reads fold into 16-bit immediates.
//     (b) preproc reverted to the R3 three-kernel form (row_start table + cvt +
//     build_w) — the fused binary search cost ~+20us of serial block-start latency.

#define M_DIM 8192
#define K_DIM 4096
#define N_DIM 4096
#define NNZ   4194304
#define FXSCALE 1048576.0f
#define FXINV  (1.0f / 1048576.0f)

#define BKT 64                 // K per tile
#define NTIL (K_DIM / BKT)     // 64 K-tiles
#define ABUF 16384             // ushorts per A/B buffer (256 rows x 64 K)

typedef __bf16 bf16x8 __attribute__((ext_vector_type(8)));
typedef float  floatx16 __attribute__((ext_vector_type(16)));
typedef unsigned short ushort8 __attribute__((ext_vector_type(8)));

__device__ __forceinline__ unsigned short f32_to_bf16(float f) {
  unsigned int u = __float_as_uint(f);
  u += 0x7FFFu + ((u >> 16) & 1u);
  return (unsigned short)(u >> 16);
}

__device__ __forceinline__ void async_copy16(const void* g, void* l) {
  __builtin_amdgcn_global_load_lds(
      (const __attribute__((address_space(1))) void*)g,
      (__attribute__((address_space(3))) void*)l,
      16, 0, 0);
}

// row_start[r] = lower_bound(rows, r); covers r in [0, N_DIM] exactly once.
__global__ void row_start_kernel(const int* __restrict__ rows,
                                 int* __restrict__ row_start) {
  int i = blockIdx.x * blockDim.x + threadIdx.x;
  if (i > NNZ) return;
  int cur  = (i < NNZ) ? rows[i] : N_DIM;
  int prev = (i > 0) ? rows[i - 1] : -1;
  for (int r = prev + 1; r <= cur; ++r) row_start[r] = i;
}

__global__ __launch_bounds__(256) void build_w_kernel(
    const float* __restrict__ vals,
    const int* __restrict__ cols,
    const int* __restrict__ row_start,
    unsigned short* __restrict__ Wb) {
  __shared__ int wrow[K_DIM];  // 16KB

  const int r = blockIdx.x;
  for (int i = threadIdx.x; i < K_DIM; i += 256) wrow[i] = 0;
  __syncthreads();

  const int start = row_start[r];
  const int end   = row_start[r + 1];
  for (int i = start + threadIdx.x; i < end; i += 256)
    atomicAdd(&wrow[cols[i]], (int)lrintf(vals[i] * FXSCALE));
  __syncthreads();

  ushort8* dst = (ushort8*)(Wb + (size_t)r * K_DIM);
  for (int i = threadIdx.x; i < K_DIM / 8; i += 256) {
    const int* s = &wrow[i * 8];
    ushort8 o;
#pragma unroll
    for (int j = 0; j < 8; j++) o[j] = f32_to_bf16((float)s[j] * FXINV);
    dst[i] = o;
  }
}

__global__ void cvt_kernel(const float4* __restrict__ in,
                           ushort4* __restrict__ out, int n4) {
  int i = blockIdx.x * blockDim.x + threadIdx.x;
  if (i < n4) {
    float4 v = in[i];
    ushort4 o;
    o.x = f32_to_bf16(v.x);
    o.y = f32_to_bf16(v.y);
    o.z = f32_to_bf16(v.z);
    o.w = f32_to_bf16(v.w);
    out[i] = o;
  }
}

// ---------------- 256x256 8-phase GEMM (32x32x16 MFMA) ----------------
#define BAR()   asm volatile("s_barrier" ::: "memory")
#define LGKM0() do { asm volatile("s_waitcnt lgkmcnt(0)" ::: "memory"); \
                     __builtin_amdgcn_sched_barrier(0); } while (0)
#define VMW6()  asm volatile("s_waitcnt vmcnt(6)" ::: "memory")
#define VMW0()  asm volatile("s_waitcnt vmcnt(0)" ::: "memory")

// stage one 16KB half-tile (128 rows x 64 K bf16): 2 global_load_lds per thread.
#define STAGEH(Gb_, Lb_, h_, kt_) do {                                          \
  async_copy16((Gb_) + (size_t)((h_)*128 +      srow) * K_DIM + (kt_),          \
               (Lb_) + (h_)*8192 +        tid * 8);                             \
  async_copy16((Gb_) + (size_t)((h_)*128 + 64 + srow) * K_DIM + (kt_),          \
               (Lb_) + (h_)*8192 + 4096 + tid * 8);                             \
} while (0)

// fragment row offsets (ushorts, compile-time):
//   A frag m (32 rows): m=0 -> mh*64; 1 -> mh*64+32; 2 -> 128+mh*64; 3 -> 160+mh*64
//   (mh*64 folded into the base pointer)
#define ROFA(m_) ((m_) == 0 ? 0 : (m_) == 1 ? 2048 : (m_) == 2 ? 8192 : 10240)
//   B frag n (32 cols): n=0 -> w32*32 (in base); n=1 -> +128 rows
#define ROFB(n_) ((n_) == 0 ? 0 : 8192)

// bi_ = 0 (buf0) or 16384 (buf1; +32768B folds into the 16-bit ds_read immediate)
#define RD_A32(bi_, mb_) do {                                                   \
  af[0][0] = *(const bf16x8*)(pAk0 + (bi_) + ROFA(mb_));                        \
  af[0][1] = *(const bf16x8*)(pAk1 + (bi_) + ROFA(mb_));                        \
  af[0][2] = *(const bf16x8*)(pAk2 + (bi_) + ROFA(mb_));                        \
  af[0][3] = *(const bf16x8*)(pAk3 + (bi_) + ROFA(mb_));                        \
  af[1][0] = *(const bf16x8*)(pAk0 + (bi_) + ROFA((mb_) + 1));                  \
  af[1][1] = *(const bf16x8*)(pAk1 + (bi_) + ROFA((mb_) + 1));                  \
  af[1][2] = *(const bf16x8*)(pAk2 + (bi_) + ROFA((mb_) + 1));                  \
  af[1][3] = *(const bf16x8*)(pAk3 + (bi_) + ROFA((mb_) + 1));                  \
} while (0)

#define RD_B32(bi_, nb_) do {                                                   \
  bf[nb_][0] = *(const bf16x8*)(pBk0 + (bi_) + ROFB(nb_));                      \
  bf[nb_][1] = *(const bf16x8*)(pBk1 + (bi_) + ROFB(nb_));                      \
  bf[nb_][2] = *(const bf16x8*)(pBk2 + (bi_) + ROFB(nb_));                      \
  bf[nb_][3] = *(const bf16x8*)(pBk3 + (bi_) + ROFB(nb_));                      \
} while (0)

#define MM32(mb_, nb_) do {                                                     \
  __builtin_amdgcn_s_setprio(1);                                                \
  _Pragma("unroll")                                                             \
  for (int ks_ = 0; ks_ < 4; ++ks_) {                                           \
    acc[(mb_)][nb_] = __builtin_amdgcn_mfma_f32_32x32x16_bf16(                  \
        af[0][ks_], bf[nb_][ks_], acc[(mb_)][nb_], 0, 0, 0);                    \
    acc[(mb_) + 1][nb_] = __builtin_amdgcn_mfma_f32_32x32x16_bf16(              \
        af[1][ks_], bf[nb_][ks_], acc[(mb_) + 1][nb_], 0, 0, 0);                \
  }                                                                             \
  __builtin_amdgcn_s_setprio(0);                                                \
} while (0)

__global__ __launch_bounds__(512, 2) void gemm_bt(
    const unsigned short* __restrict__ A,
    const unsigned short* __restrict__ B,
    float* __restrict__ C) {
  // LDS[0]=A buf0, LDS[1]=A buf1, LDS[2]=B buf0, LDS[3]=B buf1  (128 KB)
  __shared__ __attribute__((aligned(16))) unsigned short LDS[4][ABUF];

  const int tid  = threadIdx.x;
  const int wid  = tid >> 6;
  const int lane = tid & 63;
  const int l31  = lane & 31;
  const int lhi  = lane >> 5;
  const int l7   = lane & 7;
  const int mh   = wid >> 2;   // wave M-half (0/1)
  const int w32  = wid & 3;    // wave N-column (0..3)

  // XCD-aware swizzle: 512 wgs, 64 contiguous per XCD.
  int wg = blockIdx.x;
  wg = (wg & 7) * 64 + (wg >> 3);
  const int n0 = (wg & 15) * 256;
  const int m0 = (wg >> 4) * 256;

  // staging: thread t writes physical 16B block (t&7) of row (t>>3) within a
  // 64-row chunk; it fetches logical block (t&7)^(row&7) (inverse swizzle).
  const int srow = tid >> 3;
  const int sblk = ((tid & 7) ^ ((tid >> 3) & 7)) * 8;
  const unsigned short* Abase = A + (size_t)m0 * K_DIM + sblk;
  const unsigned short* Bbase = B + (size_t)n0 * K_DIM + sblk;

  // ds_read bases, one per k-step: logical 16B block = ks*2 + lhi, physical
  // block = logical ^ (row&7) = logical ^ l7 (all row bases are multiples of 8).
  //   addr = buf + (rowbase + l31)*64 + ((ks*2+lhi)^l7)*8 + ROF(frag)
  const int aB = (mh * 64 + l31) * 64;
  const int bB = (w32 * 32 + l31) * 64;
  const unsigned short* pAk0 = &LDS[0][0] + aB + (((0 + lhi) ^ l7) * 8);
  const unsigned short* pAk1 = &LDS[0][0] + aB + (((2 + lhi) ^ l7) * 8);
  const unsigned short* pAk2 = &LDS[0][0] + aB + (((4 + lhi) ^ l7) * 8);
  const unsigned short* pAk3 = &LDS[0][0] + aB + (((6 + lhi) ^ l7) * 8);
  const unsigned short* pBk0 = &LDS[2][0] + bB + (((0 + lhi) ^ l7) * 8);
  const unsigned short* pBk1 = &LDS[2][0] + bB + (((2 + lhi) ^ l7) * 8);
  const unsigned short* pBk2 = &LDS[2][0] + bB + (((4 + lhi) ^ l7) * 8);
  const unsigned short* pBk3 = &LDS[2][0] + bB + (((6 + lhi) ^ l7) * 8);

  floatx16 acc[4][2];
#pragma unroll
  for (int i = 0; i < 4; i++)
#pragma unroll
    for (int j = 0; j < 2; j++)
#pragma unroll
      for (int e = 0; e < 16; e++) acc[i][j][e] = 0.f;

  bf16x8 af[2][4], bf[2][4];

  unsigned short* A0L = &LDS[0][0];
  unsigned short* A1L = &LDS[1][0];
  unsigned short* B0L = &LDS[2][0];
  unsigned short* B1L = &LDS[3][0];

  // ---- prologue: tile0 (4 halves) + tile1 (A0,B0,A1) = 7 stages = 14 loads ----
  STAGEH(Abase, A0L, 0, 0);
  STAGEH(Bbase, B0L, 0, 0);
  STAGEH(Abase, A0L, 1, 0);
  STAGEH(Bbase, B0L, 1, 0);
  STAGEH(Abase, A1L, 0, BKT);
  STAGEH(Bbase, B1L, 0, BKT);
  STAGEH(Abase, A1L, 1, BKT);
  VMW6();   // tile0 fully landed; tile1's 3 halves still in flight
  BAR();

  // ---- main loop: 2 K-tiles per iteration, 8 phases ----
  for (int i = 0; i < NTIL / 2 - 1; ++i) {
    const int ktE = (2 * i) * BKT;
    // ======== tile E (buf0) ========
    RD_A32(0, 0); RD_B32(0, 0);
    STAGEH(Bbase, B1L, 1, ktE + BKT);        // B1(E+1) -> B buf1 [128:256)
    BAR(); LGKM0();
    MM32(0, 0);
    BAR();
    RD_B32(0, 1);
    STAGEH(Abase, A0L, 0, ktE + 2 * BKT);    // A0(E+2) -> A buf0 [0:128) (dead ph1)
    BAR(); LGKM0();
    MM32(0, 1);
    BAR();
    RD_A32(0, 2);
    STAGEH(Bbase, B0L, 0, ktE + 2 * BKT);    // B0(E+2) -> B buf0 [0:128) (dead ph1)
    BAR(); LGKM0();
    MM32(2, 0);
    BAR();
    STAGEH(Abase, A0L, 1, ktE + 2 * BKT);    // A1(E+2) -> A buf0 [128:256) (dead ph3)
    BAR();
    MM32(2, 1);
    VMW6();                                   // tile E+1 fully landed
    BAR();
    // ======== tile O = E+1 (buf1) ========
    RD_A32(16384, 0); RD_B32(16384, 0);
    STAGEH(Bbase, B0L, 1, ktE + 2 * BKT);    // B1(E+2) -> B buf0 [128:256) (dead E.ph2)
    BAR(); LGKM0();
    MM32(0, 0);
    BAR();
    RD_B32(16384, 1);
    STAGEH(Abase, A1L, 0, ktE + 3 * BKT);    // A0(E+3) -> A buf1 [0:128) (dead ph1)
    BAR(); LGKM0();
    MM32(0, 1);
    BAR();
    RD_A32(16384, 2);
    STAGEH(Bbase, B1L, 0, ktE + 3 * BKT);    // B0(E+3) -> B buf1 [0:128) (dead ph1)
    BAR(); LGKM0();
    MM32(2, 0);
    BAR();
    STAGEH(Abase, A1L, 1, ktE + 3 * BKT);    // A1(E+3) -> A buf1 [128:256) (dead ph3)
    BAR();
    MM32(2, 1);
    VMW6();                                   // tile E+2 fully landed
    BAR();
  }

  // ---- peeled last iteration: tiles NTIL-2 (buf0), NTIL-1 (buf1) ----
  {
    const int ktE = (NTIL - 2) * BKT;
    RD_A32(0, 0); RD_B32(0, 0);
    STAGEH(Bbase, B1L, 1, ktE + BKT);        // B1(NTIL-1)
    BAR(); LGKM0();
    MM32(0, 0);
    BAR();
    RD_B32(0, 1);
    BAR(); LGKM0();
    MM32(0, 1);
    BAR();
    RD_A32(0, 2);
    BAR(); LGKM0();
    MM32(2, 0);
    BAR();
    MM32(2, 1);
    VMW0();                                   // drain: tile NTIL-1 landed
    BAR();
    RD_A32(16384, 0); RD_B32(16384, 0);
    BAR(); LGKM0();
    MM32(0, 0);
    BAR();
    RD_B32(16384, 1);
    BAR(); LGKM0();
    MM32(0, 1);
    BAR();
    RD_A32(16384, 2);
    BAR(); LGKM0();
    MM32(2, 0);
    BAR();
    MM32(2, 1);
  }

  // ---- epilogue: 32x32 C/D layout: col = l&31, row = (r&3) + 8*(r>>2) + 4*lhi ----
#pragma unroll
  for (int m = 0; m < 4; m++) {
    const int arow = (m < 2 ? mh * 64 + m * 32 : 128 + mh * 64 + (m - 2) * 32);
#pragma unroll
    for (int rg = 0; rg < 4; rg++) {
#pragma unroll
      for (int rr = 0; rr < 4; rr++) {
        const int row = m0 + arow + rr + rg * 8 + lhi * 4;
        float* Cp = C + (size_t)row * N_DIM + n0 + l31;
        Cp[w32 * 32]       = acc[m][0][rg * 4 + rr];
        Cp[128 + w32 * 32] = acc[m][1][rg * 4 + rr];
      }
    }
  }
}

extern "C" void kernel_launch(void* const* d_in, const int* in_sizes, int n_in,
                              void* d_out, int out_size, void* d_ws, size_t ws_size,
                              hipStream_t stream) {
  const float* x       = (const float*)d_in[0];
  const float* values  = (const float*)d_in[1];
  const int*   col_idx = (const int*)d_in[2];
  const int*   row_ids = (const int*)d_in[3];
  float* out = (float*)d_out;

  // ws layout: [0,32MB) W bf16 | [32MB,96MB) X bf16 | [96MB,+16.4KB) row_start
  unsigned short* Wb = (unsigned short*)d_ws;
  unsigned short* Xb = (unsigned short*)((char*)d_ws + ((size_t)32 << 20));
  int* row_start     = (int*)((char*)d_ws + ((size_t)96 << 20));

  const int x4 = M_DIM * K_DIM / 4;

  row_start_kernel<<<(NNZ + 256) / 256, 256, 0, stream>>>(row_ids, row_start);
  cvt_kernel<<<(x4 + 255) / 256, 256, 0, stream>>>((const float4*)x, (ushort4*)Xb, x4);
  build_w_kernel<<<N_DIM, 256, 0, stream>>>(values, col_idx, row_start, Wb);

  gemm_bt<<<dim3(512), 512, 0, stream>>>(Xb, Wb, out);
}

// Round 5
// 458.775 us; speedup vs baseline: 1.5368x; 1.5368x over previous
//
#include <hip/hip_runtime.h>

// out = X[8192x4096] @ W^T, W[4096x4096] = scatter_add(values at (row,col)), row_ids sorted.
// R8: (a) GEMM restored to R6 exactly (16x16x32, 8 independent acc chains, base+imm
//     ds_read addressing; measured 232.7us / MfmaUtil 52 / 0 conflicts). The R7
//     32x32 experiment halved MFMA issue ILP (2 chains x 4 dependent ops) -> 2x slower.
//     (b) preproc: row_start table kept (no per-block binary search), but build_w and
//     cvt FUSED into one kernel (block-role split) so LDS-atomic work overlaps
//     BW-bound streaming. 4 launches -> 3.

#define M_DIM 8192
#define K_DIM 4096
#define N_DIM 4096
#define NNZ   4194304
#define FXSCALE 1048576.0f
#define FXINV  (1.0f / 1048576.0f)

#define BKT 64                 // K per tile
#define NTIL (K_DIM / BKT)     // 64 K-tiles
#define ABUF 16384             // ushorts per A/B buffer (256 rows x 64 K)
#define CVT_BLOCKS 8192

typedef __bf16 bf16x8 __attribute__((ext_vector_type(8)));
typedef float  floatx4 __attribute__((ext_vector_type(4)));
typedef unsigned short ushort8 __attribute__((ext_vector_type(8)));

__device__ __forceinline__ unsigned short f32_to_bf16(float f) {
  unsigned int u = __float_as_uint(f);
  u += 0x7FFFu + ((u >> 16) & 1u);
  return (unsigned short)(u >> 16);
}

__device__ __forceinline__ void async_copy16(const void* g, void* l) {
  __builtin_amdgcn_global_load_lds(
      (const __attribute__((address_space(1))) void*)g,
      (__attribute__((address_space(3))) void*)l,
      16, 0, 0);
}

// row_start[r] = lower_bound(rows, r); covers r in [0, N_DIM] exactly once.
__global__ void row_start_kernel(const int* __restrict__ rows,
                                 int* __restrict__ row_start) {
  int i = blockIdx.x * blockDim.x + threadIdx.x;
  if (i > NNZ) return;
  int cur  = (i < NNZ) ? rows[i] : N_DIM;
  int prev = (i > 0) ? rows[i - 1] : -1;
  for (int r = prev + 1; r <= cur; ++r) row_start[r] = i;
}

// Fused: blocks [0, N_DIM) build W row r (table-based bounds, LDS fixed-point
// scatter); blocks [N_DIM, N_DIM+CVT_BLOCKS) grid-stride f32->bf16 convert of X.
__global__ __launch_bounds__(256) void preproc_kernel(
    const float4* __restrict__ x4in, ushort4* __restrict__ xbout,
    const float* __restrict__ vals, const int* __restrict__ cols,
    const int* __restrict__ row_start, unsigned short* __restrict__ Wb) {
  __shared__ int wrow[K_DIM];  // 16KB (reserved for all blocks; harmless for cvt)
  if (blockIdx.x < N_DIM) {
    const int r = blockIdx.x;
    const int start = row_start[r];
    const int end   = row_start[r + 1];

    for (int i = threadIdx.x; i < K_DIM; i += 256) wrow[i] = 0;
    __syncthreads();

    for (int i = start + threadIdx.x; i < end; i += 256)
      atomicAdd(&wrow[cols[i]], (int)lrintf(vals[i] * FXSCALE));
    __syncthreads();

    ushort8* dst = (ushort8*)(Wb + (size_t)r * K_DIM);
    for (int i = threadIdx.x; i < K_DIM / 8; i += 256) {
      const int* s = &wrow[i * 8];
      ushort8 o;
#pragma unroll
      for (int j = 0; j < 8; j++) o[j] = f32_to_bf16((float)s[j] * FXINV);
      dst[i] = o;
    }
  } else {
    const int total = M_DIM * K_DIM / 4;
    for (int i = (blockIdx.x - N_DIM) * 256 + threadIdx.x; i < total;
         i += CVT_BLOCKS * 256) {
      float4 v = x4in[i];
      ushort4 o;
      o.x = f32_to_bf16(v.x);
      o.y = f32_to_bf16(v.y);
      o.z = f32_to_bf16(v.z);
      o.w = f32_to_bf16(v.w);
      xbout[i] = o;
    }
  }
}

// ---------------- 256x256 8-phase GEMM (R6, 16x16x32) ----------------
#define BAR()   asm volatile("s_barrier" ::: "memory")
#define LGKM0() do { asm volatile("s_waitcnt lgkmcnt(0)" ::: "memory"); \
                     __builtin_amdgcn_sched_barrier(0); } while (0)
#define VMW6()  asm volatile("s_waitcnt vmcnt(6)" ::: "memory")
#define VMW0()  asm volatile("s_waitcnt vmcnt(0)" ::: "memory")

// stage one 16KB half-tile (128 rows x 64 K bf16): 2 global_load_lds per thread.
#define STAGEH(Gb_, Lb_, h_, kt_) do {                                          \
  async_copy16((Gb_) + (size_t)((h_)*128 +      srow) * K_DIM + (kt_),          \
               (Lb_) + (h_)*8192 +        tid * 8);                             \
  async_copy16((Gb_) + (size_t)((h_)*128 + 64 + srow) * K_DIM + (kt_),          \
               (Lb_) + (h_)*8192 + 4096 + tid * 8);                             \
} while (0)

// fragment row offsets (ushorts; compile-time after unroll):
#define ROFA(m_) ((m_) < 4 ? (m_) * 1024 : 8192 + ((m_) - 4) * 1024)
#define ROFB(n_) ((n_) < 2 ? (n_) * 1024 : 8192 + ((n_) - 2) * 1024)

#define RD_A(p0_, p1_, mb_) do {                                                \
  _Pragma("unroll")                                                             \
  for (int m_ = 0; m_ < 4; ++m_) {                                              \
    af[m_][0] = *(const bf16x8*)((p0_) + ROFA((mb_) + m_));                     \
    af[m_][1] = *(const bf16x8*)((p1_) + ROFA((mb_) + m_));                     \
  }                                                                             \
} while (0)

#define RD_B(p0_, p1_, nb_) do {                                                \
  _Pragma("unroll")                                                             \
  for (int n_ = 0; n_ < 2; ++n_) {                                              \
    bf[(nb_) + n_][0] = *(const bf16x8*)((p0_) + ROFB((nb_) + n_));             \
    bf[(nb_) + n_][1] = *(const bf16x8*)((p1_) + ROFB((nb_) + n_));             \
  }                                                                             \
} while (0)

#define MM(mb_, nb_) do {                                                       \
  __builtin_amdgcn_s_setprio(1);                                                \
  _Pragma("unroll")                                                             \
  for (int m_ = 0; m_ < 4; ++m_)                                                \
    _Pragma("unroll")                                                           \
    for (int n_ = 0; n_ < 2; ++n_) {                                            \
      acc[(mb_) + m_][(nb_) + n_] = __builtin_amdgcn_mfma_f32_16x16x32_bf16(    \
          af[m_][0], bf[(nb_) + n_][0], acc[(mb_) + m_][(nb_) + n_], 0, 0, 0);  \
      acc[(mb_) + m_][(nb_) + n_] = __builtin_amdgcn_mfma_f32_16x16x32_bf16(    \
          af[m_][1], bf[(nb_) + n_][1], acc[(mb_) + m_][(nb_) + n_], 0, 0, 0);  \
    }                                                                           \
  __builtin_amdgcn_s_setprio(0);                                                \
} while (0)

__global__ __launch_bounds__(512, 2) void gemm_bt(
    const unsigned short* __restrict__ A,
    const unsigned short* __restrict__ B,
    float* __restrict__ C) {
  // LDS[0]=A buf0, LDS[1]=B buf0, LDS[2]=A buf1, LDS[3]=B buf1  (128 KB)
  __shared__ __attribute__((aligned(16))) unsigned short LDS[4][ABUF];

  const int tid  = threadIdx.x;
  const int wid  = tid >> 6;
  const int lane = tid & 63;
  const int quad = lane >> 4;
  const int l16  = lane & 15;
  const int mh   = wid >> 2;   // wave M-half (0/1)
  const int w32  = wid & 3;    // wave N-column (0..3)

  // XCD-aware swizzle: 512 wgs, 64 contiguous per XCD.
  int wg = blockIdx.x;
  wg = (wg & 7) * 64 + (wg >> 3);
  const int n0 = (wg & 15) * 256;
  const int m0 = (wg >> 4) * 256;

  // staging: thread t writes physical 16B block (t&7) of row (t>>3) within a
  // 64-row chunk; it fetches logical block (t&7)^(row&7) (inverse swizzle).
  const int srow = tid >> 3;
  const int sblk = ((tid & 7) ^ ((tid >> 3) & 7)) * 8;
  const unsigned short* Abase = A + (size_t)m0 * K_DIM + sblk;
  const unsigned short* Bbase = B + (size_t)n0 * K_DIM + sblk;

  // ds_read bases: row&7 == l16&7 for every fragment row, so the swizzle XOR
  // term depends only on (h, quad, l16):
  //   addr = buf + (rowbase + l16)*64 + ((h*4+quad)^(l16&7))*8 + ROF(frag)
  const int r7  = l16 & 7;
  const int xt0 = (quad ^ r7) * 8;
  const int xt1 = ((4 + quad) ^ r7) * 8;
  const int aB  = (mh * 64 + l16) * 64;
  const int bB  = (w32 * 32 + l16) * 64;

  const unsigned short* pA0h0 = &LDS[0][0] + aB + xt0;
  const unsigned short* pA0h1 = &LDS[0][0] + aB + xt1;
  const unsigned short* pB0h0 = &LDS[1][0] + bB + xt0;
  const unsigned short* pB0h1 = &LDS[1][0] + bB + xt1;
  const unsigned short* pA1h0 = &LDS[2][0] + aB + xt0;
  const unsigned short* pA1h1 = &LDS[2][0] + aB + xt1;
  const unsigned short* pB1h0 = &LDS[3][0] + bB + xt0;
  const unsigned short* pB1h1 = &LDS[3][0] + bB + xt1;

  floatx4 acc[8][4];
#pragma unroll
  for (int i = 0; i < 8; i++)
#pragma unroll
    for (int j = 0; j < 4; j++) acc[i][j] = (floatx4){0.f, 0.f, 0.f, 0.f};

  bf16x8 af[4][2], bf[4][2];

  unsigned short* A0L = &LDS[0][0];
  unsigned short* B0L = &LDS[1][0];
  unsigned short* A1L = &LDS[2][0];
  unsigned short* B1L = &LDS[3][0];

  // ---- prologue: tile0 (4 halves) + tile1 (A0,B0,A1) = 7 stages = 14 loads ----
  STAGEH(Abase, A0L, 0, 0);
  STAGEH(Bbase, B0L, 0, 0);
  STAGEH(Abase, A0L, 1, 0);
  STAGEH(Bbase, B0L, 1, 0);
  STAGEH(Abase, A1L, 0, BKT);
  STAGEH(Bbase, B1L, 0, BKT);
  STAGEH(Abase, A1L, 1, BKT);
  VMW6();   // tile0 fully landed; tile1's 3 halves still in flight
  BAR();

  // ---- main loop: 2 K-tiles per iteration, 8 phases ----
  for (int i = 0; i < NTIL / 2 - 1; ++i) {
    const int ktE = (2 * i) * BKT;
    // ======== tile E (buf0) ========
    RD_A(pA0h0, pA0h1, 0); RD_B(pB0h0, pB0h1, 0);
    STAGEH(Bbase, B1L, 1, ktE + BKT);        // B1(E+1) -> buf1 B[128:256)
    BAR(); LGKM0();
    MM(0, 0);
    BAR();
    RD_B(pB0h0, pB0h1, 2);
    STAGEH(Abase, A0L, 0, ktE + 2 * BKT);    // A0(E+2) -> buf0 A[0:128) (dead ph1)
    BAR(); LGKM0();
    MM(0, 2);
    BAR();
    RD_A(pA0h0, pA0h1, 4);
    STAGEH(Bbase, B0L, 0, ktE + 2 * BKT);    // B0(E+2) -> buf0 B[0:128) (dead ph1)
    BAR(); LGKM0();
    MM(4, 0);
    BAR();
    STAGEH(Abase, A0L, 1, ktE + 2 * BKT);    // A1(E+2) -> buf0 A[128:256) (dead ph3)
    BAR();
    MM(4, 2);
    VMW6();                                   // tile E+1 fully landed
    BAR();
    // ======== tile O = E+1 (buf1) ========
    RD_A(pA1h0, pA1h1, 0); RD_B(pB1h0, pB1h1, 0);
    STAGEH(Bbase, B0L, 1, ktE + 2 * BKT);    // B1(E+2) -> buf0 B[128:256) (dead E.ph2)
    BAR(); LGKM0();
    MM(0, 0);
    BAR();
    RD_B(pB1h0, pB1h1, 2);
    STAGEH(Abase, A1L, 0, ktE + 3 * BKT);    // A0(E+3) -> buf1 A[0:128) (dead ph1)
    BAR(); LGKM0();
    MM(0, 2);
    BAR();
    RD_A(pA1h0, pA1h1, 4);
    STAGEH(Bbase, B1L, 0, ktE + 3 * BKT);    // B0(E+3) -> buf1 B[0:128) (dead ph1)
    BAR(); LGKM0();
    MM(4, 0);
    BAR();
    STAGEH(Abase, A1L, 1, ktE + 3 * BKT);    // A1(E+3) -> buf1 A[128:256) (dead ph3)
    BAR();
    MM(4, 2);
    VMW6();                                   // tile E+2 fully landed
    BAR();
  }

  // ---- peeled last iteration: tiles NTIL-2 (buf0), NTIL-1 (buf1) ----
  {
    const int ktE = (NTIL - 2) * BKT;
    RD_A(pA0h0, pA0h1, 0); RD_B(pB0h0, pB0h1, 0);
    STAGEH(Bbase, B1L, 1, ktE + BKT);        // B1(NTIL-1)
    BAR(); LGKM0();
    MM(0, 0);
    BAR();
    RD_B(pB0h0, pB0h1, 2);
    BAR(); LGKM0();
    MM(0, 2);
    BAR();
    RD_A(pA0h0, pA0h1, 4);
    BAR(); LGKM0();
    MM(4, 0);
    BAR();
    MM(4, 2);
    VMW0();                                   // drain: tile NTIL-1 landed
    BAR();
    RD_A(pA1h0, pA1h1, 0); RD_B(pB1h0, pB1h1, 0);
    BAR(); LGKM0();
    MM(0, 0);
    BAR();
    RD_B(pB1h0, pB1h1, 2);
    BAR(); LGKM0();
    MM(0, 2);
    BAR();
    RD_A(pA1h0, pA1h1, 4);
    BAR(); LGKM0();
    MM(4, 0);
    BAR();
    MM(4, 2);
  }

  // ---- epilogue: C/D layout col = lane&15, row = quad*4 + r ----
#pragma unroll
  for (int m = 0; m < 8; m++) {
    const int mrow = (m < 4 ? mh * 64 + m * 16 : 128 + mh * 64 + (m - 4) * 16);
#pragma unroll
    for (int r = 0; r < 4; r++) {
      const int row = m0 + mrow + quad * 4 + r;
      float* Cp = C + (size_t)row * N_DIM + n0 + l16;
#pragma unroll
      for (int n = 0; n < 4; n++) {
        const int ncol = (n < 2 ? w32 * 32 + n * 16 : 128 + w32 * 32 + (n - 2) * 16);
        Cp[ncol] = acc[m][n][r];
      }
    }
  }
}

extern "C" void kernel_launch(void* const* d_in, const int* in_sizes, int n_in,
                              void* d_out, int out_size, void* d_ws, size_t ws_size,
                              hipStream_t stream) {
  const float* x       = (const float*)d_in[0];
  const float* values  = (const float*)d_in[1];
  const int*   col_idx = (const int*)d_in[2];
  const int*   row_ids = (const int*)d_in[3];
  float* out = (float*)d_out;

  // ws layout: [0,32MB) W bf16 | [32MB,96MB) X bf16 | [96MB,+16.4KB) row_start
  unsigned short* Wb = (unsigned short*)d_ws;
  unsigned short* Xb = (unsigned short*)((char*)d_ws + ((size_t)32 << 20));
  int* row_start     = (int*)((char*)d_ws + ((size_t)96 << 20));

  row_start_kernel<<<(NNZ + 256) / 256, 256, 0, stream>>>(row_ids, row_start);
  preproc_kernel<<<N_DIM + CVT_BLOCKS, 256, 0, stream>>>(
      (const float4*)x, (ushort4*)Xb, values, col_idx, row_start, Wb);

  gemm_bt<<<dim3(512), 512, 0, stream>>>(Xb, Wb, out);
}